// Round 4
// baseline (751.484 us; speedup 1.0000x reference)
//
#include <hip/hip_runtime.h>
#include <cstdint>

#define BDIM 512
#define TDIM 1024
#define EDIM 64
#define HDIM 32
#define PDIM 720

typedef float v2f __attribute__((ext_vector_type(2)));
typedef float v4f __attribute__((ext_vector_type(4)));

__device__ __forceinline__ v2f pk_fma(v2f a, v2f b, v2f c) {
    // llvm.fma.v2f32 -> v_pk_fma_f32 on gfx950; elementwise-identical to fmaf
    return __builtin_elementwise_fma(a, b, c);
}

__device__ __forceinline__ float tanh_fast(float x) {
    // tanh(x) = 1 - 2/(exp(2x)+1); exp->inf or 0 saturates correctly to +/-1
    float e = __expf(2.0f * x);
    return 1.0f - 2.0f * __builtin_amdgcn_rcpf(e + 1.0f);
}

// Cross-half (lane ^ 32) sum via v_permlane32_swap_b32 (VALU, ~10cy) instead
// of ds_bpermute-based __shfl_xor (~50cy, LDS unit). With x=y=sp on input,
// x+y after the swap equals sp[lane]+sp[lane^32] under either half-exchange
// semantics (verified algebraically for both orientations).
__device__ __forceinline__ float xhalf_sum(float sp) {
    float x = sp, y = sp;
    asm("v_permlane32_swap_b32 %0, %1" : "+v"(x), "+v"(y));
    return x + y;
}

// ---------------------------------------------------------------------------
// K1: z0[b][t][i] = sum_e x[b][t][e] * Wih0[i][e] + (bih0[i]+bhh0[i])
// Flattened rows = (b,t). 32 rows per block of 256 threads. BW-bound (~192MB).
// ---------------------------------------------------------------------------
__global__ __launch_bounds__(256) void k_zproj(
    const float* __restrict__ x, const float* __restrict__ Wih0,
    const float* __restrict__ bih0, const float* __restrict__ bhh0,
    float* __restrict__ z0)
{
    const int tid = threadIdx.x;
    const int i  = tid & 31;
    const int rg = tid >> 5;                      // 0..7
    const int64_t row0 = (int64_t)blockIdx.x * 32;

    __shared__ alignas(16) float xs[32 * 68];     // padded rows

    const float* src = x + row0 * EDIM;
    #pragma unroll
    for (int m = 0; m < 2; ++m) {
        int f = tid * 8 + m * 4;                  // coalesced: 2048 floats / block
        float4 v = *(const float4*)(src + f);
        int r = f >> 6, e = f & 63;
        *(float4*)(&xs[r * 68 + e]) = v;
    }

    float W[64];
    #pragma unroll
    for (int q = 0; q < 16; ++q) {
        float4 w = *(const float4*)(Wih0 + i * EDIM + q * 4);
        W[q*4+0] = w.x; W[q*4+1] = w.y; W[q*4+2] = w.z; W[q*4+3] = w.w;
    }
    const float bsum = bih0[i] + bhh0[i];
    __syncthreads();

    #pragma unroll
    for (int k = 0; k < 4; ++k) {
        int r = rg * 4 + k;
        const float4* xv = (const float4*)(&xs[r * 68]);  // broadcast reads
        float s0 = 0.f, s1 = 0.f, s2 = 0.f, s3 = 0.f;
        #pragma unroll
        for (int q = 0; q < 16; ++q) {
            float4 v = xv[q];
            s0 = fmaf(W[q*4+0], v.x, s0);
            s1 = fmaf(W[q*4+1], v.y, s1);
            s2 = fmaf(W[q*4+2], v.z, s2);
            s3 = fmaf(W[q*4+3], v.w, s3);
        }
        z0[(row0 + r) * HDIM + i] = bsum + ((s0 + s1) + (s2 + s3));
    }
}

// ---------------------------------------------------------------------------
// K2: fused 4-scan, split-K over lane halves, SOFTWARE-PIPELINED:
// each iteration reads the published state ONCE (h0(t), h1(t-1)) and computes
// BOTH h0(t+1) = tanh(z[t+1] + Wa.h0(t))           [layer0, one step ahead]
//  AND h1(t)   = tanh(bl1 + Wb.h0(t) + Wc.h1(t-1)) [layer1]
// -> one LDS publish->read round-trip per step (was two), and the two
// matvec+tanh chains overlap. Cross-half reduce via v_permlane32_swap_b32.
// z prefetched 4 steps ahead in a register queue (z0 is an L3-resident
// stream, ~400-600cy latency; 1-step lookahead would stall every step).
// One wave per block, ONE batch per wave; 512 blocks -> 2 waves/CU.
// Transition output overwrites this batch's own (fully consumed) z0 region.
// ---------------------------------------------------------------------------
#define DOT_HALF(W, HA, HB, HC, HD, acc0, acc1) \
    acc0 = pk_fma(W[0], HA.lo, acc0); acc1 = pk_fma(W[1], HA.hi, acc1); \
    acc0 = pk_fma(W[2], HB.lo, acc0); acc1 = pk_fma(W[3], HB.hi, acc1); \
    acc0 = pk_fma(W[4], HC.lo, acc0); acc1 = pk_fma(W[5], HC.hi, acc1); \
    acc0 = pk_fma(W[6], HD.lo, acc0); acc1 = pk_fma(W[7], HD.hi, acc1);

// One pipelined step. Reads h0/h1 chunks once; publishes h0(t+1), h1(t).
#define STEP_BODY(ZV, BLV, DO_STORE, P) do {                                 \
    v4f H0A=h0v[0], H0B=h0v[1], H0C=h0v[2], H0D=h0v[3];                      \
    v4f H1A=h1v[0], H1B=h1v[1], H1C=h1v[2], H1D=h1v[3];                      \
    v2f a0={0.f,0.f}, a1={0.f,0.f};                                          \
    DOT_HALF(Wa, H0A,H0B,H0C,H0D, a0, a1)                                    \
    v2f b0={0.f,0.f}, b1={0.f,0.f};                                          \
    DOT_HALF(Wb, H0A,H0B,H0C,H0D, b0, b1)                                    \
    DOT_HALF(Wc, H1A,H1B,H1C,H1D, b0, b1)                                    \
    v2f asv = a0 + a1, bsv = b0 + b1;                                        \
    float sA = xhalf_sum(asv.x + asv.y);                                     \
    float sB = xhalf_sum(bsv.x + bsv.y);                                     \
    float h0n = tanh_fast((ZV) + sA);                                        \
    float h1n = tanh_fast((BLV) + sB);                                       \
    hs0[woff] = h0n;                                                         \
    hs1[woff] = h1n;                                                         \
    __builtin_amdgcn_wave_barrier();                                         \
    if (DO_STORE && half == 0) dst[(P) * HDIM] = h1n;                        \
} while (0)

__global__ __launch_bounds__(64) void k_scan(
    const float* z0,                               /* aliases ts1 - no restrict */
    const float* __restrict__ eWhh0, const float* __restrict__ eWih1,
    const float* __restrict__ eWhh1,
    const float* __restrict__ ebih1, const float* __restrict__ ebhh1,
    const float* __restrict__ tWhh0, const float* __restrict__ tWih1,
    const float* __restrict__ tWhh1,
    const float* __restrict__ tbih0, const float* __restrict__ tbhh0,
    const float* __restrict__ tbih1, const float* __restrict__ tbhh1,
    float* ts1)                                    /* aliases z0 - no restrict */
{
    const int lane = threadIdx.x;
    const int half = lane >> 5;
    const int i    = lane & 31;
    const int b    = blockIdx.x;

    // real state in [0..31]; [40..71] are write-dummies for half==1
    __shared__ alignas(16) float hs0[80];
    __shared__ alignas(16) float hs1[80];

    const int woff = half * 40 + i;        // branchless publish target
    const int koff = half * 16;            // this lane's K-half base

    v2f Wa[8], Wb[8], Wc[8];
    #pragma unroll
    for (int q = 0; q < 4; ++q) {
        v4f wa = *(const v4f*)(eWhh0 + i * 32 + koff + q * 4);
        v4f wb = *(const v4f*)(eWih1 + i * 32 + koff + q * 4);
        v4f wc = *(const v4f*)(eWhh1 + i * 32 + koff + q * 4);
        Wa[2*q] = wa.lo; Wa[2*q+1] = wa.hi;
        Wb[2*q] = wb.lo; Wb[2*q+1] = wb.hi;
        Wc[2*q] = wc.lo; Wc[2*q+1] = wc.hi;
    }
    const float bl1 = ebih1[i] + ebhh1[i];

    const float* zb = z0 + (int64_t)b * TDIM * HDIM + i;
    float* dst = ts1 + (int64_t)b * TDIM * HDIM + i;

    const v4f* h0v = (const v4f*)(&hs0[koff]);
    const v4f* h1v = (const v4f*)(&hs1[koff]);

    // z prefetch queue: q0..q3 = z[1..4]
    float q0 = zb[1 * HDIM], q1 = zb[2 * HDIM], q2 = zb[3 * HDIM], q3 = zb[4 * HDIM];

    // prologue: h0(0) = tanh(z[0] + Wa.0) = tanh(z[0]);  h1(-1) = 0
    float zc0 = zb[0];
    hs0[woff] = tanh_fast(zc0);
    hs1[woff] = 0.f;
    __builtin_amdgcn_wave_barrier();

    // ---- encoder main: t = 0..1019 in blocks of 4 (255 blocks) ------------
    for (int tb = 0; tb < 1020; tb += 4) {
        int i8 = tb + 8; i8 = i8 > 1023 ? 1023 : i8;      // clamp (tb=1016 case)
        float n0 = zb[(tb + 5) * HDIM];
        float n1 = zb[(tb + 6) * HDIM];
        float n2 = zb[(tb + 7) * HDIM];
        float n3 = zb[i8 * HDIM];
        STEP_BODY(q0, bl1, false, 0);
        STEP_BODY(q1, bl1, false, 0);
        STEP_BODY(q2, bl1, false, 0);
        STEP_BODY(q3, bl1, false, 0);
        q0 = n0; q1 = n1; q2 = n2; q3 = n3;
    }
    // tail: t = 1020, 1021, 1022 (queue holds z[1021..1023])
    STEP_BODY(q0, bl1, false, 0);
    STEP_BODY(q1, bl1, false, 0);
    STEP_BODY(q2, bl1, false, 0);

    // encoder epilogue: h1(1023) from h0(1023), h1(1022); hs0 keeps hT0
    {
        v4f H0A=h0v[0], H0B=h0v[1], H0C=h0v[2], H0D=h0v[3];
        v4f H1A=h1v[0], H1B=h1v[1], H1C=h1v[2], H1D=h1v[3];
        v2f b0={0.f,0.f}, b1={0.f,0.f};
        DOT_HALF(Wb, H0A,H0B,H0C,H0D, b0, b1)
        DOT_HALF(Wc, H1A,H1B,H1C,H1D, b0, b1)
        v2f bsv = b0 + b1;
        float h1n = tanh_fast(bl1 + xhalf_sum(bsv.x + bsv.y));
        hs1[woff] = h1n;                   // hT1 published
        __builtin_amdgcn_wave_barrier();
    }

    // ---- transition: reload weights ----------------------------------------
    #pragma unroll
    for (int q = 0; q < 4; ++q) {
        v4f wa = *(const v4f*)(tWhh0 + i * 32 + koff + q * 4);
        v4f wb = *(const v4f*)(tWih1 + i * 32 + koff + q * 4);
        v4f wc = *(const v4f*)(tWhh1 + i * 32 + koff + q * 4);
        Wa[2*q] = wa.lo; Wa[2*q+1] = wa.hi;
        Wb[2*q] = wb.lo; Wb[2*q+1] = wb.hi;
        Wc[2*q] = wc.lo; Wc[2*q+1] = wc.hi;
    }
    const float zconst = tbih0[i] + tbhh0[i];   // zero-input proj = biases
    const float bl1t   = tbih1[i] + tbhh1[i];

    // transition prologue: ht0(0) = tanh(zconst + Ta.hT0)
    {
        v4f H0A=h0v[0], H0B=h0v[1], H0C=h0v[2], H0D=h0v[3];
        v2f a0={0.f,0.f}, a1={0.f,0.f};
        DOT_HALF(Wa, H0A,H0B,H0C,H0D, a0, a1)
        v2f asv = a0 + a1;
        float h0n = tanh_fast(zconst + xhalf_sum(asv.x + asv.y));
        hs0[woff] = h0n;
        __builtin_amdgcn_wave_barrier();
    }

    // transition main: p = 0..718, computes ht0(p+1) & ht1(p), stores ht1(p)
    #pragma unroll 4
    for (int p = 0; p < 719; ++p) {
        STEP_BODY(zconst, bl1t, true, p);
    }

    // transition epilogue: ht1(719) from ht0(719), ht1(718)
    {
        v4f H0A=h0v[0], H0B=h0v[1], H0C=h0v[2], H0D=h0v[3];
        v4f H1A=h1v[0], H1B=h1v[1], H1C=h1v[2], H1D=h1v[3];
        v2f b0={0.f,0.f}, b1={0.f,0.f};
        DOT_HALF(Wb, H0A,H0B,H0C,H0D, b0, b1)
        DOT_HALF(Wc, H1A,H1B,H1C,H1D, b0, b1)
        v2f bsv = b0 + b1;
        float h1n = tanh_fast(bl1t + xhalf_sum(bsv.x + bsv.y));
        if (half == 0) dst[719 * HDIM] = h1n;
    }
}

// ---------------------------------------------------------------------------
// K3: y[b][e][p0+p] = b2[e] + sum_k gelu(b1[k] + sum_j ts1[b][p][j]*W1[k][j]) * W2[e][k]
// One block = (batch b, tile of 80 p). LDS transpose for coalesced P-major
// writes. ts1 rows live at stride TDIM*HDIM per batch (z0-region reuse).
// ---------------------------------------------------------------------------
__global__ __launch_bounds__(256) void k_mlp(
    const float* __restrict__ ts1,
    const float* __restrict__ W1, const float* __restrict__ b1,
    const float* __restrict__ W2, const float* __restrict__ b2,
    float* __restrict__ out)
{
    const int b  = blockIdx.x / 9;
    const int p0 = (blockIdx.x % 9) * 80;
    const int tid = threadIdx.x;
    const int k  = tid & 63;                   // hidden (phase1) / e (phase2)
    const int pg = tid >> 6;                   // 0..3 (wave id)

    __shared__ alignas(16) float hrows[80 * 36];
    __shared__ alignas(16) float gbuf[80 * 68];
    __shared__ alignas(16) float ys[64 * 81];

    v2f W2v[32];
    #pragma unroll
    for (int q = 0; q < 16; ++q) {
        v4f w = *(const v4f*)(W2 + k * 64 + q * 4);
        W2v[2*q] = w.lo; W2v[2*q+1] = w.hi;
    }
    v2f W1v[16];
    #pragma unroll
    for (int q = 0; q < 8; ++q) {
        v4f w = *(const v4f*)(W1 + k * 32 + q * 4);
        W1v[2*q] = w.lo; W1v[2*q+1] = w.hi;
    }
    const float b1k = b1[k];
    const float b2k = b2[k];

    const float* src = ts1 + (int64_t)b * TDIM * HDIM + p0 * HDIM;  // 2560 floats
    #pragma unroll
    for (int m = 0; m < 10; ++m) {
        int f = tid + 256 * m;                 // coalesced
        hrows[(f >> 5) * 36 + (f & 31)] = src[f];
    }
    __syncthreads();

    // phase 1: gelu hidden, all 64 lanes of a wave share p (broadcast reads)
    #pragma unroll 4
    for (int m = 0; m < 20; ++m) {
        int p = pg * 20 + m;
        const v4f* hv = (const v4f*)(&hrows[p * 36]);
        v2f a0 = {0.f, 0.f}, a1 = {0.f, 0.f};
        #pragma unroll
        for (int q = 0; q < 8; ++q) {
            v4f h = hv[q];
            a0 = pk_fma(W1v[2*q],   h.lo, a0);
            a1 = pk_fma(W1v[2*q+1], h.hi, a1);
        }
        v2f as = a0 + a1;
        float a = b1k + (as.x + as.y);
        gbuf[p * 68 + k] = 0.5f * a * (1.0f + erff(a * 0.70710678118654752f));
    }
    __syncthreads();

    // phase 2: output projection, staged to ys for transposed write
    #pragma unroll 2
    for (int m = 0; m < 20; ++m) {
        int p = pg * 20 + m;
        const v4f* gv = (const v4f*)(&gbuf[p * 68]);
        v2f a0 = {0.f, 0.f}, a1 = {0.f, 0.f};
        v2f a2 = {0.f, 0.f}, a3 = {0.f, 0.f};
        #pragma unroll
        for (int q = 0; q < 16; ++q) {
            v4f g = gv[q];
            if (q & 1) {
                a2 = pk_fma(W2v[2*q],   g.lo, a2);
                a3 = pk_fma(W2v[2*q+1], g.hi, a3);
            } else {
                a0 = pk_fma(W2v[2*q],   g.lo, a0);
                a1 = pk_fma(W2v[2*q+1], g.hi, a1);
            }
        }
        v2f as = (a0 + a1) + (a2 + a3);
        ys[k * 81 + p] = b2k + (as.x + as.y);
    }
    __syncthreads();

    // phase 3: coalesced float4 writes along P
    const int e = tid >> 2, pq = tid & 3;
    float* obase = out + (int64_t)b * EDIM * PDIM + (int64_t)e * PDIM + p0;
    #pragma unroll
    for (int m = 0; m < 5; ++m) {
        int p = (pq + 4 * m) * 4;
        float4 v = make_float4(ys[e*81+p+0], ys[e*81+p+1],
                               ys[e*81+p+2], ys[e*81+p+3]);
        *(float4*)(obase + p) = v;
    }
}

// ---------------------------------------------------------------------------
extern "C" void kernel_launch(void* const* d_in, const int* in_sizes, int n_in,
                              void* d_out, int out_size, void* d_ws, size_t ws_size,
                              hipStream_t stream)
{
    const float* x      = (const float*)d_in[0];
    const float* eWih0  = (const float*)d_in[1];
    const float* eWhh0  = (const float*)d_in[2];
    const float* ebih0  = (const float*)d_in[3];
    const float* ebhh0  = (const float*)d_in[4];
    const float* eWih1  = (const float*)d_in[5];
    const float* eWhh1  = (const float*)d_in[6];
    const float* ebih1  = (const float*)d_in[7];
    const float* ebhh1  = (const float*)d_in[8];
    /* d_in[9] = t_Wih0: dead (zero-input transition) */
    const float* tWhh0  = (const float*)d_in[10];
    const float* tbih0  = (const float*)d_in[11];
    const float* tbhh0  = (const float*)d_in[12];
    const float* tWih1  = (const float*)d_in[13];
    const float* tWhh1  = (const float*)d_in[14];
    const float* tbih1  = (const float*)d_in[15];
    const float* tbhh1  = (const float*)d_in[16];
    const float* oW1    = (const float*)d_in[17];
    const float* ob1    = (const float*)d_in[18];
    const float* oW2    = (const float*)d_in[19];
    const float* ob2    = (const float*)d_in[20];

    float* z0  = (float*)d_ws;              // 64 MB; ts1 reuses it in-place
    float* outp = (float*)d_out;

    k_zproj<<<BDIM * TDIM / 32, 256, 0, stream>>>(x, eWih0, ebih0, ebhh0, z0);
    k_scan<<<BDIM, 64, 0, stream>>>(z0, eWhh0, eWih1, eWhh1, ebih1, ebhh1,
                                    tWhh0, tWih1, tWhh1,
                                    tbih0, tbhh0, tbih1, tbhh1, z0);
    k_mlp<<<BDIM * 9, 256, 0, stream>>>(z0, oW1, ob1, oW2, ob2, outp);
}